// Round 6
// baseline (213.901 us; speedup 1.0000x reference)
//
#include <hip/hip_runtime.h>

#define NB 8
#define NS 2048
#define ND 512
#define QB 64
#define KB 256
#define NKT (NS / KB)   // 8

#define QP 520   // Q LDS pitch (shorts): 512 + 8
#define PP 264   // P LDS pitch (shorts): 256 + 8

// LDS offsets (bytes)
#define QS_OFF   0         // 64*520*2 = 66560
#define PS_OFF   66560     // 64*264*2 = 33792
#define TMAX_OFF 100352    // 64*8*4   = 2048
#define TSUM_OFF 102400    // 2048
#define MROW_OFF 104448    // 2*64*4   = 512
#define AROW_OFF 104960    // 256
#define LROW_OFF 105216    // 256
#define LDS_BYTES 105472

typedef __attribute__((ext_vector_type(4)))  float f32x4;
typedef __attribute__((ext_vector_type(16))) float f32x16;
typedef __attribute__((ext_vector_type(8)))  short s16x8;

__device__ __forceinline__ unsigned short f2bf(float f) {
    unsigned int u = __float_as_uint(f);
    u += 0x7FFF + ((u >> 16) & 1);
    return (unsigned short)(u >> 16);
}

// ---- pre-pass: Q,K fp32 -> bf16 (Q pre-scaled by 1/sqrt(D)) ----
__global__ void cvt_qk_kernel(const float* __restrict__ Q, const float* __restrict__ K,
                              unsigned short* __restrict__ Qb, unsigned short* __restrict__ Kb) {
    const float scale = 0.04419417382415922f;
    size_t i = ((size_t)blockIdx.x * 256 + threadIdx.x) * 4;
    float4 q = *(const float4*)(Q + i);
    float4 k = *(const float4*)(K + i);
    ushort4 qo, ko;
    qo.x = f2bf(q.x * scale); qo.y = f2bf(q.y * scale);
    qo.z = f2bf(q.z * scale); qo.w = f2bf(q.w * scale);
    ko.x = f2bf(k.x); ko.y = f2bf(k.y); ko.z = f2bf(k.z); ko.w = f2bf(k.w);
    *(ushort4*)(Qb + i) = qo;
    *(ushort4*)(Kb + i) = ko;
}

// ---- pre-pass: V fp32 [b][s][d] -> V^T bf16 [b][d][s] ----
__global__ void cvt_vt_kernel(const float* __restrict__ V, unsigned short* __restrict__ Vt) {
    __shared__ float tile[32][33];
    int bid = blockIdx.x;
    int dt = bid & 15;
    int st = (bid >> 4) & 63;
    int b  = bid >> 10;
    int t = threadIdx.x;
    int sl = t >> 3, dq = t & 7;
    const float* src = V + ((size_t)b * NS + st * 32 + sl) * ND + dt * 32 + dq * 4;
    float4 v = *(const float4*)src;
    tile[sl][dq * 4 + 0] = v.x; tile[sl][dq * 4 + 1] = v.y;
    tile[sl][dq * 4 + 2] = v.z; tile[sl][dq * 4 + 3] = v.w;
    __syncthreads();
    int dl = t >> 3, sq = t & 7;
    ushort4 o;
    o.x = f2bf(tile[sq * 4 + 0][dl]);
    o.y = f2bf(tile[sq * 4 + 1][dl]);
    o.z = f2bf(tile[sq * 4 + 2][dl]);
    o.w = f2bf(tile[sq * 4 + 3][dl]);
    *(ushort4*)(Vt + ((size_t)b * ND + dt * 32 + dl) * NS + st * 32 + sq * 4) = o;
}

// ---- main flash-attention kernel ----
// grid 256; 1024 threads (16 waves, 4/SIMD); b = blockIdx&7 (XCD affinity: batch K+V = 4MB = one L2).
// QK^T swapped (A=K,B=Q), 32x32x16: wave (wk=w&7, wq=w>>3) owns k-rows [wk*32,+32), q-half wq*32.
// PV 16x16x32: wave w owns output d-cols [w*32, w*32+32).
__global__ void __launch_bounds__(1024, 4) attn_kernel(const unsigned short* __restrict__ Qg_,
                                                       const unsigned short* __restrict__ Kg_,
                                                       const unsigned short* __restrict__ Vg_,
                                                       float* __restrict__ out) {
    extern __shared__ __align__(16) char smem[];
    unsigned short* Qs = (unsigned short*)(smem + QS_OFF);   // [64][QP]
    unsigned short* Ps = (unsigned short*)(smem + PS_OFF);   // [64][PP]
    float* tmax = (float*)(smem + TMAX_OFF);                 // [64][8]
    float* tsum = (float*)(smem + TSUM_OFF);                 // [64][8]
    float* mrow = (float*)(smem + MROW_OFF);                 // [2][64]
    float* arow = (float*)(smem + AROW_OFF);                 // [64]
    float* lrow = (float*)(smem + LROW_OFF);                 // [64]

    const int tid  = threadIdx.x;
    const int lane = tid & 63;
    const int w    = tid >> 6;     // 0..15
    const int wk   = w & 7;        // QK k-block
    const int wq   = w >> 3;       // QK q-half
    const int hi   = lane >> 5;    // 0/1
    const int l31  = lane & 31;
    const int g    = lane >> 4;    // 0..3 (PV)
    const int c    = lane & 15;    // 0..15 (PV)
    const int b    = blockIdx.x & 7;
    const int qt   = blockIdx.x >> 3;

    const unsigned short* Qg = Qg_ + ((size_t)b * NS + qt * QB) * ND;
    const unsigned short* Kg = Kg_ + (size_t)b * NS * ND;
    const unsigned short* Vg = Vg_ + (size_t)b * ND * NS;   // [512][2048]

    // stage Q tile (64 x 512), padded pitch
    #pragma unroll
    for (int it = 0; it < 4; ++it) {
        int idx = it * 8192 + tid * 8;
        int r = idx >> 9, cc = idx & 511;
        *(s16x8*)(Qs + r * QP + cc) = *(const s16x8*)(Qg + idx);
    }
    if (tid < 64) { mrow[tid] = -INFINITY; lrow[tid] = 0.f; }
    __syncthreads();

    f32x4 o[4][2];   // O[q = qb*16 + g*4 + r][d = w*32 + nb*16 + c]
    #pragma unroll
    for (int i = 0; i < 4; ++i)
        for (int j = 0; j < 2; ++j) o[i][j] = (f32x4){0.f, 0.f, 0.f, 0.f};

    // K A-frag base: row = wk*32 + l31, d-slice offset hi*8
    const unsigned short* Kp = Kg + (size_t)(wk * 32 + l31) * ND + hi * 8;
    // V B-frag base: d-row = w*32 + c, k-offset g*8
    const unsigned short* Vp = Vg + (size_t)(w * 32 + c) * NS + g * 8;

    // 4-deep K fragment ring
    s16x8 kr[4];
    #pragma unroll
    for (int p = 0; p < 4; ++p) kr[p] = *(const s16x8*)(Kp + p * 16);

    for (int kt = 0; kt < NKT; ++kt) {
        const size_t kts = (size_t)kt * KB;
        const unsigned short* K0 = Kp + kts * ND;
        const unsigned short* Kn = Kp + (kts + KB) * ND;

        // ---- QK^T: sc = S[k = wk*32 + crow(r,hi)][q = wq*32 + l31] ----
        f32x16 sc = (f32x16)0.f;
        #pragma unroll
        for (int s = 0; s < 32; ++s) {
            const int rg = s & 3;
            s16x8 qf = *(const s16x8*)(Qs + (wq * 32 + l31) * QP + s * 16 + hi * 8);
            __builtin_amdgcn_s_setprio(1);
            sc = __builtin_amdgcn_mfma_f32_32x32x16_bf16(kr[rg], qf, sc, 0, 0, 0);
            __builtin_amdgcn_s_setprio(0);
            if (s < 28)
                kr[rg] = *(const s16x8*)(K0 + (s + 4) * 16);
            else if (kt < NKT - 1)
                kr[rg] = *(const s16x8*)(Kn + (s - 28) * 16);
        }

        // issue V ks=0,1 early (hide L2 latency under softmax)
        s16x8 bv[2][2];
        #pragma unroll
        for (int ks = 0; ks < 2; ++ks)
            #pragma unroll
            for (int nb = 0; nb < 2; ++nb)
                bv[ks][nb] = *(const s16x8*)(Vp + (size_t)nb * 16 * NS + kts + ks * 32);

        // ---- wave-local per-q max over wave's 32 k ----
        {
            float m0 = sc[0];
            #pragma unroll
            for (int r = 1; r < 16; ++r) m0 = fmaxf(m0, sc[r]);
            m0 = fmaxf(m0, __shfl_xor(m0, 32));
            if (lane < 32) tmax[(wq * 32 + l31) * 8 + wk] = m0;
        }
        __syncthreads();                                     // B1
        const int par = kt & 1;
        {   // cooperative max/alpha (16 dup writers per row, same value)
            int row = tid & 63;
            f32x4 t0 = *(const f32x4*)(tmax + row * 8);
            f32x4 t1 = *(const f32x4*)(tmax + row * 8 + 4);
            float mx = fmaxf(fmaxf(fmaxf(t0[0], t0[1]), fmaxf(t0[2], t0[3])),
                             fmaxf(fmaxf(t1[0], t1[1]), fmaxf(t1[2], t1[3])));
            float mo = mrow[par * 64 + row];
            float mn = fmaxf(mo, mx);
            mrow[(par ^ 1) * 64 + row] = mn;
            arow[row] = __expf(mo - mn);
        }
        __syncthreads();                                     // B2

        // ---- P = exp(S-m), row sum, P -> LDS packed ----
        {
            const int q = wq * 32 + l31;
            float mq = mrow[(par ^ 1) * 64 + q];
            #pragma unroll
            for (int r = 0; r < 16; ++r) sc[r] = __expf(sc[r] - mq);
            float s0 = 0.f;
            #pragma unroll
            for (int r = 0; r < 16; ++r) s0 += sc[r];
            s0 += __shfl_xor(s0, 32);
            if (lane < 32) tsum[q * 8 + wk] = s0;
            #pragma unroll
            for (int rg = 0; rg < 4; ++rg) {   // k = wk*32 + rg*8 + hi*4 + 0..3
                ushort4 pk;
                pk.x = f2bf(sc[rg * 4 + 0]); pk.y = f2bf(sc[rg * 4 + 1]);
                pk.z = f2bf(sc[rg * 4 + 2]); pk.w = f2bf(sc[rg * 4 + 3]);
                *(ushort4*)(Ps + q * PP + wk * 32 + rg * 8 + hi * 4) = pk;
            }
        }
        // rescale O by alpha
        #pragma unroll
        for (int qb = 0; qb < 4; ++qb)
            #pragma unroll
            for (int r = 0; r < 4; ++r) {
                float al = arow[qb * 16 + g * 4 + r];
                #pragma unroll
                for (int nb = 0; nb < 2; ++nb) o[qb][nb][r] *= al;
            }
        __syncthreads();                                     // B3
        if (tid < 64) {
            int row = tid;
            f32x4 s0 = *(const f32x4*)(tsum + row * 8);
            f32x4 s1 = *(const f32x4*)(tsum + row * 8 + 4);
            float ls = (s0[0] + s0[1] + s0[2] + s0[3]) + (s1[0] + s1[1] + s1[2] + s1[3]);
            lrow[row] = lrow[row] * arow[row] + ls;
        }

        // ---- PV: O[64 x 32(w)] += P(64x256) @ V(256x32) ----
        #pragma unroll
        for (int ks = 0; ks < 8; ++ks) {
            const int sl = ks & 1;
            s16x8 ap[4];
            #pragma unroll
            for (int qb = 0; qb < 4; ++qb)
                ap[qb] = *(const s16x8*)(Ps + (qb * 16 + c) * PP + ks * 32 + g * 8);
            __builtin_amdgcn_s_setprio(1);
            #pragma unroll
            for (int qb = 0; qb < 4; ++qb)
                #pragma unroll
                for (int nb = 0; nb < 2; ++nb)
                    o[qb][nb] = __builtin_amdgcn_mfma_f32_16x16x32_bf16(ap[qb], bv[sl][nb], o[qb][nb], 0, 0, 0);
            __builtin_amdgcn_s_setprio(0);
            if (ks < 6)
                #pragma unroll
                for (int nb = 0; nb < 2; ++nb)
                    bv[sl][nb] = *(const s16x8*)(Vp + (size_t)nb * 16 * NS + kts + (ks + 2) * 32);
        }
    }

    __syncthreads();
    float* Og = out + ((size_t)b * NS + qt * QB) * ND;
    #pragma unroll
    for (int qb = 0; qb < 4; ++qb)
        #pragma unroll
        for (int r = 0; r < 4; ++r) {
            float li = 1.f / lrow[qb * 16 + g * 4 + r];
            #pragma unroll
            for (int nb = 0; nb < 2; ++nb)
                Og[(size_t)(qb * 16 + g * 4 + r) * ND + w * 32 + nb * 16 + c] =
                    o[qb][nb][r] * li;
        }
}

extern "C" void kernel_launch(void* const* d_in, const int* in_sizes, int n_in,
                              void* d_out, int out_size, void* d_ws, size_t ws_size,
                              hipStream_t stream) {
    const float* V = (const float*)d_in[0];
    const float* K = (const float*)d_in[1];
    const float* Q = (const float*)d_in[2];
    float* out = (float*)d_out;

    unsigned short* Qb = (unsigned short*)d_ws;
    unsigned short* Kb = Qb + (size_t)NB * NS * ND;
    unsigned short* Vt = Kb + (size_t)NB * NS * ND;

    hipFuncSetAttribute(reinterpret_cast<const void*>(attn_kernel),
                        hipFuncAttributeMaxDynamicSharedMemorySize, LDS_BYTES);

    cvt_qk_kernel<<<8192, 256, 0, stream>>>(Q, K, Qb, Kb);
    cvt_vt_kernel<<<8192, 256, 0, stream>>>(V, Vt);
    attn_kernel<<<NB * (NS / QB), 1024, LDS_BYTES, stream>>>(Qb, Kb, Vt, out);
}

// Round 7
// 155.523 us; speedup vs baseline: 1.3754x; 1.3754x over previous
//
#include <hip/hip_runtime.h>

#define NB 8
#define NS 2048
#define ND 512
#define QB 64
#define KB 256
#define NKT (NS / KB)   // 8
#define M_FIX 14.0f

// LDS offsets (bytes); Qs/Ps XOR-swizzled, no padding
#define QS_OFF   0         // 64*512*2 = 65536
#define PS_OFF   65536     // 2 * 64*256*2 = 65536
#define TSUM_OFF 131072    // 64*8*4 = 2048
#define LROW_OFF 133120    // 256
#define LDS_BYTES 133376

typedef __attribute__((ext_vector_type(4)))  float f32x4;
typedef __attribute__((ext_vector_type(16))) float f32x16;
typedef __attribute__((ext_vector_type(8)))  short s16x8;

__device__ __forceinline__ unsigned short f2bf(float f) {
    unsigned int u = __float_as_uint(f);
    u += 0x7FFF + ((u >> 16) & 1);
    return (unsigned short)(u >> 16);
}

// ---- pre-pass: Q,K fp32 -> bf16 (Q pre-scaled by 1/sqrt(D)) ----
__global__ void cvt_qk_kernel(const float* __restrict__ Q, const float* __restrict__ K,
                              unsigned short* __restrict__ Qb, unsigned short* __restrict__ Kb) {
    const float scale = 0.04419417382415922f;
    size_t i = ((size_t)blockIdx.x * 256 + threadIdx.x) * 4;
    float4 q = *(const float4*)(Q + i);
    float4 k = *(const float4*)(K + i);
    ushort4 qo, ko;
    qo.x = f2bf(q.x * scale); qo.y = f2bf(q.y * scale);
    qo.z = f2bf(q.z * scale); qo.w = f2bf(q.w * scale);
    ko.x = f2bf(k.x); ko.y = f2bf(k.y); ko.z = f2bf(k.z); ko.w = f2bf(k.w);
    *(ushort4*)(Qb + i) = qo;
    *(ushort4*)(Kb + i) = ko;
}

// ---- pre-pass: V fp32 [b][s][d] -> V^T bf16 [b][d][s] ----
__global__ void cvt_vt_kernel(const float* __restrict__ V, unsigned short* __restrict__ Vt) {
    __shared__ float tile[32][33];
    int bid = blockIdx.x;
    int dt = bid & 15;
    int st = (bid >> 4) & 63;
    int b  = bid >> 10;
    int t = threadIdx.x;
    int sl = t >> 3, dq = t & 7;
    const float* src = V + ((size_t)b * NS + st * 32 + sl) * ND + dt * 32 + dq * 4;
    float4 v = *(const float4*)src;
    tile[sl][dq * 4 + 0] = v.x; tile[sl][dq * 4 + 1] = v.y;
    tile[sl][dq * 4 + 2] = v.z; tile[sl][dq * 4 + 3] = v.w;
    __syncthreads();
    int dl = t >> 3, sq = t & 7;
    ushort4 o;
    o.x = f2bf(tile[sq * 4 + 0][dl]);
    o.y = f2bf(tile[sq * 4 + 1][dl]);
    o.z = f2bf(tile[sq * 4 + 2][dl]);
    o.w = f2bf(tile[sq * 4 + 3][dl]);
    *(ushort4*)(Vt + ((size_t)b * ND + dt * 32 + dl) * NS + st * 32 + sq * 4) = o;
}

// ---- main flash-attention kernel (fixed-max softmax, pipelined) ----
// grid 256; 512 threads (8 waves); b = blockIdx&7 (XCD affinity: batch K+V = 4MB = one L2).
// QK^T swapped (A=K,B=Q) 32x32x16: wave w owns k-rows [w*32,+32); sc[qb] = S[k][q=qb*32+l31].
// PV 32x32x16 (A=P,B=V): wave w owns output d-cols [w*64,+64); o[qb][db] = O[q][d=w*64+db*32+l31].
// P double-buffered in LDS; PV(kt-1) interleaved with QK(kt); ONE barrier per kt.
__global__ void __launch_bounds__(512, 2) attn_kernel(const unsigned short* __restrict__ Qg_,
                                                      const unsigned short* __restrict__ Kg_,
                                                      const unsigned short* __restrict__ Vg_,
                                                      float* __restrict__ out) {
    extern __shared__ __align__(16) char smem[];
    unsigned short* Qs  = (unsigned short*)(smem + QS_OFF);   // [64][512] swizzled
    unsigned short* Ps0 = (unsigned short*)(smem + PS_OFF);   // [2][64][256] swizzled
    float* tsum = (float*)(smem + TSUM_OFF);                  // [64][8]
    float* lrow = (float*)(smem + LROW_OFF);                  // [64]

    const int tid  = threadIdx.x;
    const int lane = tid & 63;
    const int w    = tid >> 6;     // 0..7
    const int hi   = lane >> 5;    // 0/1
    const int l31  = lane & 31;
    const int b    = blockIdx.x & 7;
    const int qt   = blockIdx.x >> 3;

    const unsigned short* Qg = Qg_ + ((size_t)b * NS + qt * QB) * ND;
    const unsigned short* Kg = Kg_ + (size_t)b * NS * ND;
    const unsigned short* Vg = Vg_ + (size_t)b * ND * NS;   // [512][2048]

    // stage Q tile (64 x 512), swizzled: col ^= (row&7)<<3 (shorts)
    #pragma unroll
    for (int it = 0; it < 8; ++it) {
        int idx = it * 4096 + tid * 8;
        int r = idx >> 9, cc = idx & 511;
        *(s16x8*)(Qs + r * 512 + (cc ^ ((r & 7) << 3))) = *(const s16x8*)(Qg + idx);
    }
    __syncthreads();

    f32x16 o00 = (f32x16)0.f, o01 = (f32x16)0.f, o10 = (f32x16)0.f, o11 = (f32x16)0.f;
    float ls0 = 0.f, ls1 = 0.f;

    const unsigned short* Kp = Kg + (size_t)(w * 32 + l31) * ND + hi * 8;
    const unsigned short* Vr0 = Vg + (size_t)(w * 64 + l31) * NS + hi * 8;
    const unsigned short* Vr1 = Vg + (size_t)(w * 64 + 32 + l31) * NS + hi * 8;
    const int qsw = (l31 & 7) << 3;

    // 4-deep K fragment ring
    s16x8 kr[4];
    #pragma unroll
    for (int p = 0; p < 4; ++p) kr[p] = *(const s16x8*)(Kp + p * 16);

    // ---- softmax finish + P write (shared by all iterations) ----
    auto finishP = [&](f32x16& sc0, f32x16& sc1, unsigned short* Pcur) {
        #pragma unroll
        for (int r = 0; r < 16; ++r) { sc0[r] = __expf(sc0[r] - M_FIX); sc1[r] = __expf(sc1[r] - M_FIX); }
        float a0 = 0.f, a1 = 0.f;
        #pragma unroll
        for (int r = 0; r < 16; ++r) { a0 += sc0[r]; a1 += sc1[r]; }
        ls0 += a0; ls1 += a1;
        #pragma unroll
        for (int rg = 0; rg < 4; ++rg) {   // k = w*32 + rg*8 + hi*4 + 0..3
            ushort4 p0, p1;
            p0.x = f2bf(sc0[rg * 4 + 0]); p0.y = f2bf(sc0[rg * 4 + 1]);
            p0.z = f2bf(sc0[rg * 4 + 2]); p0.w = f2bf(sc0[rg * 4 + 3]);
            p1.x = f2bf(sc1[rg * 4 + 0]); p1.y = f2bf(sc1[rg * 4 + 1]);
            p1.z = f2bf(sc1[rg * 4 + 2]); p1.w = f2bf(sc1[rg * 4 + 3]);
            *(ushort4*)(Pcur + (l31) * 256 + ((w * 32 + rg * 8 + hi * 4) ^ qsw)) = p0;
            *(ushort4*)(Pcur + (32 + l31) * 256 + ((w * 32 + rg * 8 + hi * 4) ^ qsw)) = p1;
        }
    };

    // ======== kt = 0: QK only ========
    {
        f32x16 sc0 = (f32x16)0.f, sc1 = (f32x16)0.f;
        const unsigned short* K0 = Kp;
        #pragma unroll
        for (int s = 0; s < 32; ++s) {
            const int rg = s & 3;
            s16x8 qf0 = *(const s16x8*)(Qs + l31 * 512        + ((s * 16 + hi * 8) ^ qsw));
            s16x8 qf1 = *(const s16x8*)(Qs + (32 + l31) * 512 + ((s * 16 + hi * 8) ^ qsw));
            sc0 = __builtin_amdgcn_mfma_f32_32x32x16_bf16(kr[rg], qf0, sc0, 0, 0, 0);
            sc1 = __builtin_amdgcn_mfma_f32_32x32x16_bf16(kr[rg], qf1, sc1, 0, 0, 0);
            if (s < 28) kr[rg] = *(const s16x8*)(K0 + (s + 4) * 16);
            else        kr[rg] = *(const s16x8*)(K0 + (size_t)KB * ND + (s - 28) * 16);
        }
        finishP(sc0, sc1, Ps0);
        __syncthreads();
    }

    // ======== kt = 1..7: QK(kt) interleaved with PV(kt-1) ========
    for (int kt = 1; kt < NKT; ++kt) {
        const unsigned short* Kcur = Kp + (size_t)kt * KB * ND;
        const unsigned short* Kn   = Kcur + (size_t)KB * ND;
        unsigned short* Pprev = Ps0 + ((kt - 1) & 1) * 16384;
        unsigned short* Pcur  = Ps0 + (kt & 1) * 16384;
        const size_t kvp = (size_t)(kt - 1) * KB;

        f32x16 sc0 = (f32x16)0.f, sc1 = (f32x16)0.f;
        // initial V fragments (ks=0)
        s16x8 bvc0 = *(const s16x8*)(Vr0 + kvp);
        s16x8 bvc1 = *(const s16x8*)(Vr1 + kvp);
        s16x8 bvn0, bvn1;

        #pragma unroll
        for (int u = 0; u < 16; ++u) {
            // --- QK step 2u ---
            {
                const int s = 2 * u, rg = s & 3;
                s16x8 qf0 = *(const s16x8*)(Qs + l31 * 512        + ((s * 16 + hi * 8) ^ qsw));
                s16x8 qf1 = *(const s16x8*)(Qs + (32 + l31) * 512 + ((s * 16 + hi * 8) ^ qsw));
                sc0 = __builtin_amdgcn_mfma_f32_32x32x16_bf16(kr[rg], qf0, sc0, 0, 0, 0);
                sc1 = __builtin_amdgcn_mfma_f32_32x32x16_bf16(kr[rg], qf1, sc1, 0, 0, 0);
                if (s < 28)            kr[rg] = *(const s16x8*)(Kcur + (s + 4) * 16);
                else if (kt < NKT - 1) kr[rg] = *(const s16x8*)(Kn + (s - 28) * 16);
            }
            // --- PV step u (tile kt-1) ---
            {
                s16x8 ap0 = *(const s16x8*)(Pprev + l31 * 256        + ((u * 16 + hi * 8) ^ qsw));
                s16x8 ap1 = *(const s16x8*)(Pprev + (32 + l31) * 256 + ((u * 16 + hi * 8) ^ qsw));
                if (u < 15) {
                    bvn0 = *(const s16x8*)(Vr0 + kvp + (u + 1) * 16);
                    bvn1 = *(const s16x8*)(Vr1 + kvp + (u + 1) * 16);
                }
                o00 = __builtin_amdgcn_mfma_f32_32x32x16_bf16(ap0, bvc0, o00, 0, 0, 0);
                o01 = __builtin_amdgcn_mfma_f32_32x32x16_bf16(ap0, bvc1, o01, 0, 0, 0);
                o10 = __builtin_amdgcn_mfma_f32_32x32x16_bf16(ap1, bvc0, o10, 0, 0, 0);
                o11 = __builtin_amdgcn_mfma_f32_32x32x16_bf16(ap1, bvc1, o11, 0, 0, 0);
            }
            // --- QK step 2u+1 ---
            {
                const int s = 2 * u + 1, rg = s & 3;
                s16x8 qf0 = *(const s16x8*)(Qs + l31 * 512        + ((s * 16 + hi * 8) ^ qsw));
                s16x8 qf1 = *(const s16x8*)(Qs + (32 + l31) * 512 + ((s * 16 + hi * 8) ^ qsw));
                sc0 = __builtin_amdgcn_mfma_f32_32x32x16_bf16(kr[rg], qf0, sc0, 0, 0, 0);
                sc1 = __builtin_amdgcn_mfma_f32_32x32x16_bf16(kr[rg], qf1, sc1, 0, 0, 0);
                if (s < 28)            kr[rg] = *(const s16x8*)(Kcur + (s + 4) * 16);
                else if (kt < NKT - 1) kr[rg] = *(const s16x8*)(Kn + (s - 28) * 16);
            }
            bvc0 = bvn0; bvc1 = bvn1;
        }
        finishP(sc0, sc1, Pcur);
        __syncthreads();
    }

    // ======== epilogue: PV(7) ========
    {
        unsigned short* Pprev = Ps0 + ((NKT - 1) & 1) * 16384;
        const size_t kvp = (size_t)(NKT - 1) * KB;
        s16x8 bvc0 = *(const s16x8*)(Vr0 + kvp);
        s16x8 bvc1 = *(const s16x8*)(Vr1 + kvp);
        s16x8 bvn0, bvn1;
        #pragma unroll
        for (int u = 0; u < 16; ++u) {
            s16x8 ap0 = *(const s16x8*)(Pprev + l31 * 256        + ((u * 16 + hi * 8) ^ qsw));
            s16x8 ap1 = *(const s16x8*)(Pprev + (32 + l31) * 256 + ((u * 16 + hi * 8) ^ qsw));
            if (u < 15) {
                bvn0 = *(const s16x8*)(Vr0 + kvp + (u + 1) * 16);
                bvn1 = *(const s16x8*)(Vr1 + kvp + (u + 1) * 16);
            }
            o00 = __builtin_amdgcn_mfma_f32_32x32x16_bf16(ap0, bvc0, o00, 0, 0, 0);
            o01 = __builtin_amdgcn_mfma_f32_32x32x16_bf16(ap0, bvc1, o01, 0, 0, 0);
            o10 = __builtin_amdgcn_mfma_f32_32x32x16_bf16(ap1, bvc0, o10, 0, 0, 0);
            o11 = __builtin_amdgcn_mfma_f32_32x32x16_bf16(ap1, bvc1, o11, 0, 0, 0);
            bvc0 = bvn0; bvc1 = bvn1;
        }
    }

    // ======== l finalize + output ========
    ls0 += __shfl_xor(ls0, 32);
    ls1 += __shfl_xor(ls1, 32);
    if (lane < 32) {
        tsum[l31 * 8 + w]        = ls0;
        tsum[(32 + l31) * 8 + w] = ls1;
    }
    __syncthreads();
    if (tid < 64) {
        f32x4 s0 = *(const f32x4*)(tsum + tid * 8);
        f32x4 s1 = *(const f32x4*)(tsum + tid * 8 + 4);
        lrow[tid] = 1.f / ((s0[0] + s0[1] + s0[2] + s0[3]) + (s1[0] + s1[1] + s1[2] + s1[3]));
    }
    __syncthreads();

    float* Og = out + ((size_t)b * NS + qt * QB) * ND;
    #pragma unroll
    for (int r = 0; r < 16; ++r) {
        const int crow = (r & 3) + 8 * (r >> 2) + 4 * hi;
        float li0 = lrow[crow];
        float li1 = lrow[32 + crow];
        Og[(size_t)crow * ND + w * 64 + l31]             = o00[r] * li0;
        Og[(size_t)crow * ND + w * 64 + 32 + l31]        = o01[r] * li0;
        Og[(size_t)(32 + crow) * ND + w * 64 + l31]      = o10[r] * li1;
        Og[(size_t)(32 + crow) * ND + w * 64 + 32 + l31] = o11[r] * li1;
    }
}

extern "C" void kernel_launch(void* const* d_in, const int* in_sizes, int n_in,
                              void* d_out, int out_size, void* d_ws, size_t ws_size,
                              hipStream_t stream) {
    const float* V = (const float*)d_in[0];
    const float* K = (const float*)d_in[1];
    const float* Q = (const float*)d_in[2];
    float* out = (float*)d_out;

    unsigned short* Qb = (unsigned short*)d_ws;
    unsigned short* Kb = Qb + (size_t)NB * NS * ND;
    unsigned short* Vt = Kb + (size_t)NB * NS * ND;

    hipFuncSetAttribute(reinterpret_cast<const void*>(attn_kernel),
                        hipFuncAttributeMaxDynamicSharedMemorySize, LDS_BYTES);

    cvt_qk_kernel<<<8192, 256, 0, stream>>>(Q, K, Qb, Kb);
    cvt_vt_kernel<<<8192, 256, 0, stream>>>(V, Vt);
    attn_kernel<<<NB * (NS / QB), 512, LDS_BYTES, stream>>>(Qb, Kb, Vt, out);
}